// Round 7
// baseline (457.148 us; speedup 1.0000x reference)
//
#include <hip/hip_runtime.h>

#define B_ 8
#define S_ 1024
#define C_ 512
#define H_ 8
#define D_ 64
#define P_ 16
#define SP_ 1040    // valid keys: S + P
#define SPAD_ 1088  // score-matrix row stride: 17*64
#define KSZ 3

typedef unsigned short u16;
typedef short bf16x8 __attribute__((ext_vector_type(8)));
typedef float f32x4 __attribute__((ext_vector_type(4)));

__device__ __forceinline__ float bf2f(u16 u) {
  return __uint_as_float(((unsigned int)u) << 16);
}
__device__ __forceinline__ u16 f2bf(float f) {
  unsigned int u = __float_as_uint(f);
  return (u16)((u + 0x7fffu + ((u >> 16) & 1u)) >> 16);
}
// Packed fp32->bf16 RNE convert: 1 instr for 2 values (same rounding as f2bf).
__device__ __forceinline__ unsigned int cvtpk(float lo, float hi) {
  unsigned int r;
  asm("v_cvt_pk_bf16_f32 %0, %1, %2" : "=v"(r) : "v"(lo), "v"(hi));
  return r;
}
// Raw v_exp_f32: computes 2^x in one instruction.
__device__ __forceinline__ float exp2v(float x) {
  float r;
  asm("v_exp_f32 %0, %1" : "=v"(r) : "v"(x));
  return r;
}
// Round 8 consecutive fp32 to bf16, packed as int4 (8 x u16).
__device__ __forceinline__ int4 pack8(const float* p) {
  int4 r;
  r.x = (int)cvtpk(p[0], p[1]);
  r.y = (int)cvtpk(p[2], p[3]);
  r.z = (int)cvtpk(p[4], p[5]);
  r.w = (int)cvtpk(p[6], p[7]);
  return r;
}

// Merged prep: x cvt | Wfc cvt + conv repacks | k/v prefix | Wq/Wk/Wv cvt.
__global__ void k_prep(const float* x, u16* xb, const float* Wfc, u16* wfcb,
                       const float* c1w, u16* w1t, const float* c2w, u16* w2t,
                       const float* Wq, const float* Wk, const float* Wv,
                       u16* wb3, const float* pk, const float* pv, u16* kb,
                       u16* vtb) {
  int b = blockIdx.x, tid = threadIdx.x;
  if (b < 2048) {  // x fp32 -> bf16, 8 elems/thread
    int gid = b * 256 + tid;
    *(int4*)&xb[(size_t)gid * 8] = pack8(&x[(size_t)gid * 8]);
    return;
  }
  if (b < 9216) {  // Wfc cvt + conv1/conv2 repack
    int gid = (b - 2048) * 256 + tid;
    if (gid < C_ * C_) {
      wfcb[gid] = f2bf(Wfc[gid]);
      return;
    }
    int r = gid - C_ * C_;
    const float* src = c1w;
    u16* dst = w1t;
    if (r >= C_ * C_ * KSZ) {
      r -= C_ * C_ * KSZ;
      src = c2w;
      dst = w2t;
    }
    int co = r / (C_ * KSZ);
    int rem = r - co * (C_ * KSZ);
    int ci = rem / KSZ;
    int tap = rem - ci * KSZ;
    dst[(size_t)tap * C_ * C_ + co * C_ + ci] = f2bf(src[r]);
    return;
  }
  if (b < 10240) {  // prefix rows: kb[S..SPAD) + vtb[.., 1024..1088)
    int g = (b - 9216) * 256 + tid;  // 262144
    {
      int d = g & 63, t = g >> 6, p = t & 63, nh = t >> 6;
      kb[((size_t)nh * SPAD_ + S_ + p) * D_ + d] =
          (p < P_) ? f2bf(pk[p * 64 + d]) : 0;
    }
    {
      int p = g & 63, d = (g >> 6) & 63, nh = g >> 12;
      vtb[((size_t)nh * D_ + d) * SPAD_ + S_ + p] =
          (p < P_) ? f2bf(pv[p * 64 + d]) : 0;
    }
    return;
  }
  {  // Wq/Wk/Wv -> bf16 wb3[mat][64][64]
    int e = (b - 10240) * 256 + tid;  // 12288
    int mat = e >> 12, idx = e & 4095;
    const float* W = (mat == 0) ? Wq : ((mat == 1) ? Wk : Wv);
    wb3[e] = f2bf(W[idx]);
  }
}

// QKV: per (mat, head) NT-GEMM via MFMA, M=B*S, N=64, K=64.
// W pre-converted (wb3); V written directly transposed to vtb via LDS bounce.
__global__ __launch_bounds__(256) void k_qkv(
    const u16* xb, const u16* wb3, u16* qb, u16* kb, u16* vtb) {
  __shared__ u16 As[64][72];
  __shared__ u16 Bs[64][72];
  int tid = threadIdx.x;
  int lin = blockIdx.x + 128 * blockIdx.y;        // 3072 blocks
  lin = (lin & 7) * (3072 >> 3) + (lin >> 3);     // bijective XCD chunking
  int m0 = (lin / 24) * 64;
  int yy = lin % 24;
  int mat = yy >> 3, h = yy & 7;
  for (int u = tid; u < 512; u += 256) {
    int row = u >> 3, seg = u & 7;
    *(int4*)&As[row][seg * 8] =
        *(const int4*)&xb[(size_t)(m0 + row) * C_ + h * 64 + seg * 8];
    *(int4*)&Bs[row][seg * 8] =
        *(const int4*)&wb3[(mat << 12) + row * 64 + seg * 8];
  }
  __syncthreads();
  int w = tid >> 6, lane = tid & 63, qd = lane >> 4, l15 = lane & 15;
  f32x4 acc[4] = {};
  for (int ks = 0; ks < 2; ++ks) {
    bf16x8 a = *(const bf16x8*)&As[w * 16 + l15][ks * 32 + qd * 8];
    for (int t = 0; t < 4; ++t) {
      bf16x8 b = *(const bf16x8*)&Bs[t * 16 + l15][ks * 32 + qd * 8];
      acc[t] = __builtin_amdgcn_mfma_f32_16x16x32_bf16(a, b, acc[t], 0, 0, 0);
    }
  }
  int n = m0 >> 10, s0 = m0 & 1023;
  if (mat == 2) {
    // transpose in LDS: As[d][s_local] then coalesced store to vtb[nh][d][s].
    __syncthreads();
    for (int t = 0; t < 4; ++t)
      for (int r = 0; r < 4; ++r)
        As[t * 16 + l15][w * 16 + qd * 4 + r] = f2bf(acc[t][r]);
    __syncthreads();
    int nh = n * H_ + h;
    for (int u = tid; u < 512; u += 256) {
      int d = u >> 3, seg = u & 7;
      *(int4*)&vtb[((size_t)nh * D_ + d) * SPAD_ + s0 + seg * 8] =
          *(const int4*)&As[d][seg * 8];
    }
    return;
  }
  for (int t = 0; t < 4; ++t)
    for (int r = 0; r < 4; ++r) {
      int s = s0 + w * 16 + qd * 4 + r;
      int d = t * 16 + l15;
      u16 val = f2bf(acc[t][r]);
      if (mat == 0)
        qb[((size_t)(n * H_ + h) * S_ + s) * D_ + d] = val;
      else
        kb[((size_t)(n * H_ + h) * SPAD_ + s) * D_ + d] = val;
    }
}

// Energy: Sb[nh][q][l] = q.k via MFMA.
// R7: LDS-free -- MFMA fragments are plain row-slices; A bytes were read
// from LDS exactly once (zero reuse), B 4x (L1-served). No barriers.
__global__ __launch_bounds__(256) void k_energy(const u16* __restrict__ qb,
                                                const u16* __restrict__ kb,
                                                u16* __restrict__ Sb) {
  int tid = threadIdx.x;
  int lin = blockIdx.x + 17 * (blockIdx.y + 16 * blockIdx.z);  // 17408
  lin = (lin & 7) * (17408 >> 3) + (lin >> 3);
  int l0 = (lin % 17) * 64;
  int t0 = lin / 17;
  int q0 = (t0 & 15) * 64;
  int nh = t0 >> 4;  // n*H + h
  int w = tid >> 6, lane = tid & 63, qd = lane >> 4, l15 = lane & 15;
  const u16* qrow = qb + ((size_t)nh * S_ + q0 + w * 16 + l15) * D_ + qd * 8;
  const u16* krow = kb + ((size_t)nh * SPAD_ + l0 + l15) * D_ + qd * 8;
  f32x4 acc[4] = {};
#pragma unroll
  for (int ks = 0; ks < 2; ++ks) {
    bf16x8 a = *(const bf16x8*)&qrow[ks * 32];
#pragma unroll
    for (int t = 0; t < 4; ++t) {
      bf16x8 b = *(const bf16x8*)&krow[(size_t)t * 16 * D_ + ks * 32];
      acc[t] = __builtin_amdgcn_mfma_f32_16x16x32_bf16(a, b, acc[t], 0, 0, 0);
    }
  }
  for (int t = 0; t < 4; ++t)
    for (int r = 0; r < 4; ++r) {
      int q = q0 + w * 16 + qd * 4 + r;
      int l = l0 + t * 16 + l15;
      Sb[((size_t)nh * S_ + q) * SPAD_ + l] = f2bf(acc[t][r]);
    }
}

// Per (n,q): premix (W_pre + folded ALiBi), softmax over l<SP, postmix.
// No max pass (shift-invariance; bounded range). Weights via s_load.
__global__ __launch_bounds__(256) void k_smx(u16* __restrict__ Sb,
                                             const float* __restrict__ Wpre,
                                             const float* __restrict__ Wpost) {
  __shared__ __align__(16) float red[8][36];  // [head][group], 32 groups
  __shared__ __align__(16) float izf[8];      // 1/sum per head
  int tid = threadIdx.x;
  int n = blockIdx.x >> 10, q = blockIdx.x & 1023;
  const size_t hs = (size_t)S_ * SPAD_;
  u16* __restrict__ base = Sb + ((size_t)n * H_ * S_ + q) * SPAD_;
  // 1/sqrt(512) * log2(e): softmax in exp2 domain (exact same math).
  const float isc2 = 0.04419417382415922f * 1.4426950408889634f;

  int la = 4 * tid;
  bool hasB = (tid < 16);
  int lb = 1024 + tid;  // 16 valid prefix keys

  // Issue all global loads up front (MLP).
  uint2 ldA[8];
#pragma unroll
  for (int i = 0; i < 8; ++i) ldA[i] = *(const uint2*)(base + i * hs + la);
  u16 ldB[8];
  if (hasB) {
#pragma unroll
    for (int i = 0; i < 8; ++i) ldB[i] = base[i * hs + lb];
  }

  float bt[4];
#pragma unroll
  for (int j = 0; j < 4; ++j) bt[j] = -fabsf((float)(q - (la + j)));

  // ---------- premix chunk A (bias folded into inputs) ----------
  float eA[32];  // [o][4]
#pragma unroll
  for (int j = 0; j < 32; ++j) eA[j] = 0.f;
#pragma unroll
  for (int i = 0; i < 8; ++i) {
    const float ci = 1.0f / (float)(2 << i);  // 2^-(i+1), compile-time
    float x0 = bf2f((u16)(ldA[i].x & 0xffffu)) + bt[0] * ci;
    float x1 = bf2f((u16)(ldA[i].x >> 16)) + bt[1] * ci;
    float x2 = bf2f((u16)(ldA[i].y & 0xffffu)) + bt[2] * ci;
    float x3 = bf2f((u16)(ldA[i].y >> 16)) + bt[3] * ci;
#pragma unroll
    for (int o = 0; o < 8; ++o) {
      float wv = Wpre[o * 8 + i];  // uniform -> s_load, SGPR operand
      eA[4 * o + 0] += wv * x0;
      eA[4 * o + 1] += wv * x1;
      eA[4 * o + 2] += wv * x2;
      eA[4 * o + 3] += wv * x3;
    }
  }

  // ---------- premix tail: 16 prefix keys, 1 per thread, no bias ----------
  float eB[8];
  if (hasB) {
#pragma unroll
    for (int o = 0; o < 8; ++o) eB[o] = 0.f;
#pragma unroll
    for (int i = 0; i < 8; ++i) {
      float xi = bf2f(ldB[i]);
#pragma unroll
      for (int o = 0; o < 8; ++o) eB[o] += Wpre[o * 8 + i] * xi;
    }
  }

  // ---------- exp2 (no shift) + block-wide sum ----------
  float zl[8];
#pragma unroll
  for (int o = 0; o < 8; ++o) {
    float s = 0.f;
#pragma unroll
    for (int j = 0; j < 4; ++j) {
      eA[4 * o + j] = exp2v(eA[4 * o + j] * isc2);
      s += eA[4 * o + j];
    }
    zl[o] = s;
  }
  if (hasB) {
#pragma unroll
    for (int o = 0; o < 8; ++o) {
      eB[o] = exp2v(eB[o] * isc2);
      zl[o] += eB[o];
    }
  }
#pragma unroll
  for (int o = 0; o < 8; ++o)
    for (int mm = 1; mm < 8; mm <<= 1) zl[o] += __shfl_xor(zl[o], mm, 64);
  {
    int g = tid >> 3;
    if ((tid & 7) == 0) {
#pragma unroll
      for (int o = 0; o < 8; ++o) red[o][g] = zl[o];
    }
  }
  __syncthreads();
  if (tid < 64) {
    int o = tid >> 3, part = tid & 7;
    f32x4 pv = *(const f32x4*)&red[o][part * 4];
    float ps = (pv[0] + pv[1]) + (pv[2] + pv[3]);
    for (int mm = 1; mm < 8; mm <<= 1) ps += __shfl_xor(ps, mm, 64);
    if (part == 0) izf[o] = 1.0f / ps;
  }
  __syncthreads();

  f32x4 zlo = *(const f32x4*)&izf[0];
  f32x4 zhi = *(const f32x4*)&izf[4];

  // ---------- normalize + postmix + store, chunk A ----------
  {
#pragma unroll
    for (int o = 0; o < 8; ++o) {
      float iz = (o < 4) ? zlo[o & 3] : zhi[o & 3];
#pragma unroll
      for (int j = 0; j < 4; ++j) eA[4 * o + j] *= iz;
    }
#pragma unroll
    for (int o = 0; o < 8; ++o) {
      float p0 = 0.f, p1 = 0.f, p2 = 0.f, p3 = 0.f;
#pragma unroll
      for (int i = 0; i < 8; ++i) {
        float wv = Wpost[o * 8 + i];  // uniform -> s_load
        p0 += wv * eA[4 * i + 0];
        p1 += wv * eA[4 * i + 1];
        p2 += wv * eA[4 * i + 2];
        p3 += wv * eA[4 * i + 3];
      }
      uint2 u;
      u.x = cvtpk(p0, p1);
      u.y = cvtpk(p2, p3);
      *(uint2*)(base + o * hs + la) = u;
    }
  }
  // ---------- normalize + postmix + store, tail ----------
  if (hasB) {
#pragma unroll
    for (int o = 0; o < 8; ++o) {
      float iz = (o < 4) ? zlo[o & 3] : zhi[o & 3];
      eB[o] *= iz;
    }
#pragma unroll
    for (int o = 0; o < 8; ++o) {
      float p0 = 0.f;
#pragma unroll
      for (int i = 0; i < 8; ++i) p0 += Wpost[o * 8 + i] * eB[i];
      base[o * hs + lb] = f2bf(p0);
    }
  }
}

// AV: attb = attn @ vT. R7: LDS-free direct-operand MFMA, no barriers.
// A (P tile) bytes have zero reuse; B (vT, 139KB/nh) served by L1/L2.
__global__ __launch_bounds__(256) void k_av(const u16* __restrict__ Sb,
                                            const u16* __restrict__ vtb,
                                            u16* __restrict__ attb) {
  int tid = threadIdx.x;
  int lin = blockIdx.x + 16 * blockIdx.y;  // 1024 blocks
  lin = (lin & 7) * (1024 >> 3) + (lin >> 3);
  int q0 = (lin & 15) * 64;
  int nh = lin >> 4;
  int n = nh >> 3, h = nh & 7;
  int w = tid >> 6, lane = tid & 63, qd = lane >> 4, l15 = lane & 15;
  const u16* arow =
      Sb + ((size_t)nh * S_ + q0 + w * 16 + l15) * SPAD_ + qd * 8;
  const u16* brow = vtb + ((size_t)nh * D_ + l15) * SPAD_ + qd * 8;
  f32x4 acc[4] = {};
#pragma unroll 2
  for (int k = 0; k < 34; ++k) {
    int off = k * 32;
    bf16x8 a = *(const bf16x8*)&arow[off];
#pragma unroll
    for (int t = 0; t < 4; ++t) {
      bf16x8 b = *(const bf16x8*)&brow[(size_t)t * 16 * SPAD_ + off];
      acc[t] = __builtin_amdgcn_mfma_f32_16x16x32_bf16(a, b, acc[t], 0, 0, 0);
    }
  }
  for (int t = 0; t < 4; ++t)
    for (int r = 0; r < 4; ++r) {
      int q = q0 + w * 16 + qd * 4 + r;
      int c = h * 64 + t * 16 + l15;
      attb[((size_t)(n * S_ + q)) * C_ + c] = f2bf(acc[t][r]);
    }
}

// FC + residual: hp = x + att @ Wfc^T + bfc (fp32 out).
// R7: LDS-free direct-operand MFMA, no barriers.
__global__ __launch_bounds__(256) void k_fc(const u16* __restrict__ attb,
                                            const u16* __restrict__ Wfcb,
                                            const float* __restrict__ bfc,
                                            const float* __restrict__ x,
                                            float* __restrict__ hp) {
  int tid = threadIdx.x;
  int lin = blockIdx.x + 128 * blockIdx.y;  // 1024 blocks
  lin = (lin & 7) * (1024 >> 3) + (lin >> 3);
  int m0 = (lin & 127) * 64, n0 = (lin >> 7) * 64;
  int w = tid >> 6, lane = tid & 63, qd = lane >> 4, l15 = lane & 15;
  const u16* arow = attb + (size_t)(m0 + w * 16 + l15) * C_ + qd * 8;
  const u16* brow = Wfcb + (size_t)(n0 + l15) * C_ + qd * 8;
  f32x4 acc[4] = {};
#pragma unroll 2
  for (int k = 0; k < 16; ++k) {
    int off = k * 32;
    bf16x8 a = *(const bf16x8*)&arow[off];
#pragma unroll
    for (int t = 0; t < 4; ++t) {
      bf16x8 b = *(const bf16x8*)&brow[(size_t)t * 16 * C_ + off];
      acc[t] = __builtin_amdgcn_mfma_f32_16x16x32_bf16(a, b, acc[t], 0, 0, 0);
    }
  }
  for (int t = 0; t < 4; ++t)
    for (int r = 0; r < 4; ++r) {
      int m = m0 + w * 16 + qd * 4 + r;
      int c = n0 + t * 16 + l15;
      hp[(size_t)m * C_ + c] = acc[t][r] + bfc[c] + x[(size_t)m * C_ + c];
    }
}

// LayerNorm over C per row; fp32 in, bf16 out.
__global__ __launch_bounds__(512) void k_ln(const float* hp, const float* g,
                                            const float* b, u16* hb) {
  __shared__ float r1[8], r2[8];
  int row = blockIdx.x, tid = threadIdx.x;
  int w = tid >> 6, lane = tid & 63;
  float v = hp[(size_t)row * C_ + tid];
  float s1 = v, s2 = v * v;
  for (int m = 1; m < 64; m <<= 1) {
    s1 += __shfl_xor(s1, m, 64);
    s2 += __shfl_xor(s2, m, 64);
  }
  if (lane == 0) {
    r1[w] = s1;
    r2[w] = s2;
  }
  __syncthreads();
  float t1 = 0.f, t2 = 0.f;
  for (int i = 0; i < 8; ++i) {
    t1 += r1[i];
    t2 += r2[i];
  }
  float mu = t1 * (1.0f / C_);
  float var = t2 * (1.0f / C_) - mu * mu;
  float o = (v - mu) * rsqrtf(var + 1e-5f) * g[tid] + b[tid];
  hb[(size_t)row * C_ + tid] = f2bf(o);
}

// Causal conv (K=3, left pad 2) as 3 accumulated MFMA NT-GEMMs.
// LDS-staged (kept: 3-tap B reuse), s-tile 64, K-step 64, XCD swizzle.
// mode 0: out = relu(acc+bias) -> outb bf16
// mode 1: out = relu(relu(acc+bias)+res) -> outf fp32
__global__ __launch_bounds__(256) void k_conv(const u16* in, const u16* wt,
                                              const float* bias,
                                              const u16* res, u16* outb,
                                              float* outf, int mode) {
  __shared__ u16 As[66][72];
  __shared__ u16 Bs[3][64][72];
  int tid = threadIdx.x;
  int lin = blockIdx.x + 128 * blockIdx.y;  // 1024 blocks
  lin = (lin & 7) * (1024 >> 3) + (lin >> 3);
  int m0 = (lin & 127) * 64, n0 = (lin >> 7) * 64;
  int n = m0 >> 10, s0 = m0 & 1023;
  int w = tid >> 6, lane = tid & 63, qd = lane >> 4, l15 = lane & 15;
  f32x4 acc[4] = {};
  for (int ks = 0; ks < 8; ++ks) {
    int k0 = ks * 64;
    __syncthreads();
    for (int u = tid; u < 528; u += 256) {
      int row = u >> 3, seg = u & 7;
      int s = s0 + row - 2;
      int4 pa;
      pa.x = pa.y = pa.z = pa.w = 0;
      if (s >= 0)
        pa = *(const int4*)&in[((size_t)(n * S_ + s)) * C_ + k0 + seg * 8];
      *(int4*)&As[row][seg * 8] = pa;
    }
    for (int u = tid; u < 1536; u += 256) {
      int tap = u >> 9, rr = (u >> 3) & 63, seg = u & 7;
      *(int4*)&Bs[tap][rr][seg * 8] = *(const int4*)&wt[
          (size_t)tap * C_ * C_ + (size_t)(n0 + rr) * C_ + k0 + seg * 8];
    }
    __syncthreads();
    for (int k2 = 0; k2 < 2; ++k2) {
      for (int tap = 0; tap < 3; ++tap) {
        bf16x8 a = *(const bf16x8*)&As[w * 16 + l15 + tap][k2 * 32 + qd * 8];
        for (int t = 0; t < 4; ++t) {
          bf16x8 b = *(const bf16x8*)&Bs[tap][t * 16 + l15][k2 * 32 + qd * 8];
          acc[t] =
              __builtin_amdgcn_mfma_f32_16x16x32_bf16(a, b, acc[t], 0, 0, 0);
        }
      }
    }
  }
  for (int t = 0; t < 4; ++t)
    for (int r = 0; r < 4; ++r) {
      int s = s0 + w * 16 + qd * 4 + r;
      int c = n0 + t * 16 + l15;
      float val = fmaxf(acc[t][r] + bias[c], 0.0f);
      size_t idx = ((size_t)(n * S_ + s)) * C_ + c;
      if (mode) {
        val = fmaxf(val + bf2f(res[idx]), 0.0f);
        outf[idx] = val;
      } else {
        outb[idx] = f2bf(val);
      }
    }
}

extern "C" void kernel_launch(void* const* d_in, const int* in_sizes, int n_in,
                              void* d_out, int out_size, void* d_ws,
                              size_t ws_size, hipStream_t stream) {
  int o = (in_sizes[1] == D_ * D_) ? 1 : 2;  // dict vs signature order
  const float* x = (const float*)d_in[0];
  const float* Wq = (const float*)d_in[o + 0];
  const float* Wk = (const float*)d_in[o + 1];
  const float* Wv = (const float*)d_in[o + 2];
  const float* Wfc = (const float*)d_in[o + 3];
  const float* bfc = (const float*)d_in[o + 4];
  const float* Wpre = (const float*)d_in[o + 5];
  const float* Wpost = (const float*)d_in[o + 6];
  const float* pk = (const float*)d_in[o + 7];
  const float* pv = (const float*)d_in[o + 8];
  const float* lng = (const float*)d_in[o + 9];
  const float* lnb = (const float*)d_in[o + 10];
  const float* c1w = (const float*)d_in[o + 11];
  const float* c1b = (const float*)d_in[o + 12];
  const float* c2w = (const float*)d_in[o + 13];
  const float* c2b = (const float*)d_in[o + 14];
  float* out = (float*)d_out;

  // Workspace ~215 MB (ws_size = 256 MiB per the harness poison fill).
  char* ws = (char*)d_ws;
  size_t off = 0;
  u16* qb = (u16*)(ws + off);   off += (size_t)B_ * H_ * S_ * D_ * 2;
  u16* kb = (u16*)(ws + off);   off += (size_t)B_ * H_ * SPAD_ * D_ * 2;
  u16* vtb = (u16*)(ws + off);  off += (size_t)B_ * H_ * D_ * SPAD_ * 2;
  u16* Sb = (u16*)(ws + off);   off += (size_t)B_ * H_ * S_ * SPAD_ * 2;  // 142.6MB
  u16* attb = (u16*)(ws + off); off += (size_t)B_ * S_ * C_ * 2;
  float* hp = (float*)(ws + off); off += (size_t)B_ * S_ * C_ * 4;
  u16* hb = (u16*)(ws + off);   off += (size_t)B_ * S_ * C_ * 2;
  u16* o1b = (u16*)(ws + off);  off += (size_t)B_ * S_ * C_ * 2;
  u16* wfcb = (u16*)(ws + off); off += (size_t)C_ * C_ * 2;
  u16* w1t = (u16*)(ws + off);  off += (size_t)KSZ * C_ * C_ * 2;
  u16* w2t = (u16*)(ws + off);  off += (size_t)KSZ * C_ * C_ * 2;
  u16* xb = (u16*)(ws + off);   off += (size_t)B_ * S_ * C_ * 2;
  u16* wb3 = (u16*)(ws + off);  off += (size_t)3 * D_ * D_ * 2;

  k_prep<<<10288, 256, 0, stream>>>(x, xb, Wfc, wfcb, c1w, w1t, c2w, w2t,
                                    Wq, Wk, Wv, wb3, pk, pv, kb, vtb);
  k_qkv<<<dim3(128, 24), 256, 0, stream>>>(xb, wb3, qb, kb, vtb);
  k_energy<<<dim3(17, 16, 64), 256, 0, stream>>>(qb, kb, Sb);
  k_smx<<<8192, 256, 0, stream>>>(Sb, Wpre, Wpost);
  k_av<<<dim3(16, 64), 256, 0, stream>>>(Sb, vtb, attb);
  k_fc<<<dim3(128, 8), 256, 0, stream>>>(attb, wfcb, bfc, x, hp);
  k_ln<<<8192, 512, 0, stream>>>(hp, lng, lnb, hb);
  k_conv<<<dim3(128, 8), 256, 0, stream>>>(hb, w1t, c1b, (const u16*)0, o1b,
                                           (float*)0, 0);
  k_conv<<<dim3(128, 8), 256, 0, stream>>>(o1b, w2t, c2b, hb, (u16*)0, out, 1);
}

// Round 8
// 325.507 us; speedup vs baseline: 1.4044x; 1.4044x over previous
//
#include <hip/hip_runtime.h>

#define B_ 8
#define S_ 1024
#define C_ 512
#define H_ 8
#define D_ 64
#define P_ 16
#define SP_ 1040    // valid keys: S + P
#define SPAD_ 1088  // score-matrix row stride: 17*64
#define KSZ 3

typedef unsigned short u16;
typedef unsigned int u32;
typedef short bf16x8 __attribute__((ext_vector_type(8)));
typedef float f32x4 __attribute__((ext_vector_type(4)));

__device__ __forceinline__ float bf2f(u16 u) {
  return __uint_as_float(((unsigned int)u) << 16);
}
__device__ __forceinline__ u16 f2bf(float f) {
  unsigned int u = __float_as_uint(f);
  return (u16)((u + 0x7fffu + ((u >> 16) & 1u)) >> 16);
}
// Packed fp32->bf16 RNE convert: 1 instr for 2 values (same rounding as f2bf).
__device__ __forceinline__ unsigned int cvtpk(float lo, float hi) {
  unsigned int r;
  asm("v_cvt_pk_bf16_f32 %0, %1, %2" : "=v"(r) : "v"(lo), "v"(hi));
  return r;
}
// Raw v_exp_f32: computes 2^x in one instruction.
__device__ __forceinline__ float exp2v(float x) {
  float r;
  asm("v_exp_f32 %0, %1" : "=v"(r) : "v"(x));
  return r;
}
// Async global->LDS, 16B per lane. LDS dest is wave-uniform base + lane*16.
__device__ __forceinline__ void glds16(const u16* g, u16* l) {
  __builtin_amdgcn_global_load_lds(
      (const __attribute__((address_space(1))) u32*)g,
      (__attribute__((address_space(3))) u32*)l, 16, 0, 0);
}
// Round 8 consecutive fp32 to bf16, packed as int4 (8 x u16).
__device__ __forceinline__ int4 pack8(const float* p) {
  int4 r;
  r.x = (int)cvtpk(p[0], p[1]);
  r.y = (int)cvtpk(p[2], p[3]);
  r.z = (int)cvtpk(p[4], p[5]);
  r.w = (int)cvtpk(p[6], p[7]);
  return r;
}

// Merged prep: x cvt | Wfc cvt + conv repacks | k/v prefix | Wq/Wk/Wv cvt.
__global__ void k_prep(const float* x, u16* xb, const float* Wfc, u16* wfcb,
                       const float* c1w, u16* w1t, const float* c2w, u16* w2t,
                       const float* Wq, const float* Wk, const float* Wv,
                       u16* wb3, const float* pk, const float* pv, u16* kb,
                       u16* vtb) {
  int b = blockIdx.x, tid = threadIdx.x;
  if (b < 2048) {  // x fp32 -> bf16, 8 elems/thread
    int gid = b * 256 + tid;
    *(int4*)&xb[(size_t)gid * 8] = pack8(&x[(size_t)gid * 8]);
    return;
  }
  if (b < 9216) {  // Wfc cvt + conv1/conv2 repack
    int gid = (b - 2048) * 256 + tid;
    if (gid < C_ * C_) {
      wfcb[gid] = f2bf(Wfc[gid]);
      return;
    }
    int r = gid - C_ * C_;
    const float* src = c1w;
    u16* dst = w1t;
    if (r >= C_ * C_ * KSZ) {
      r -= C_ * C_ * KSZ;
      src = c2w;
      dst = w2t;
    }
    int co = r / (C_ * KSZ);
    int rem = r - co * (C_ * KSZ);
    int ci = rem / KSZ;
    int tap = rem - ci * KSZ;
    dst[(size_t)tap * C_ * C_ + co * C_ + ci] = f2bf(src[r]);
    return;
  }
  if (b < 10240) {  // prefix rows: kb[S..SPAD) + vtb[.., 1024..1088)
    int g = (b - 9216) * 256 + tid;  // 262144
    {
      int d = g & 63, t = g >> 6, p = t & 63, nh = t >> 6;
      kb[((size_t)nh * SPAD_ + S_ + p) * D_ + d] =
          (p < P_) ? f2bf(pk[p * 64 + d]) : 0;
    }
    {
      int p = g & 63, d = (g >> 6) & 63, nh = g >> 12;
      vtb[((size_t)nh * D_ + d) * SPAD_ + S_ + p] =
          (p < P_) ? f2bf(pv[p * 64 + d]) : 0;
    }
    return;
  }
  {  // Wq/Wk/Wv -> bf16 wb3[mat][64][64]
    int e = (b - 10240) * 256 + tid;  // 12288
    int mat = e >> 12, idx = e & 4095;
    const float* W = (mat == 0) ? Wq : ((mat == 1) ? Wk : Wv);
    wb3[e] = f2bf(W[idx]);
  }
}

// QKV: per (mat, head) NT-GEMM via MFMA, M=B*S, N=64, K=64.
// W pre-converted (wb3); V written directly transposed to vtb via LDS bounce.
__global__ __launch_bounds__(256) void k_qkv(
    const u16* xb, const u16* wb3, u16* qb, u16* kb, u16* vtb) {
  __shared__ u16 As[64][72];
  __shared__ u16 Bs[64][72];
  int tid = threadIdx.x;
  int lin = blockIdx.x + 128 * blockIdx.y;        // 3072 blocks
  lin = (lin & 7) * (3072 >> 3) + (lin >> 3);     // bijective XCD chunking
  int m0 = (lin / 24) * 64;
  int yy = lin % 24;
  int mat = yy >> 3, h = yy & 7;
  for (int u = tid; u < 512; u += 256) {
    int row = u >> 3, seg = u & 7;
    *(int4*)&As[row][seg * 8] =
        *(const int4*)&xb[(size_t)(m0 + row) * C_ + h * 64 + seg * 8];
    *(int4*)&Bs[row][seg * 8] =
        *(const int4*)&wb3[(mat << 12) + row * 64 + seg * 8];
  }
  __syncthreads();
  int w = tid >> 6, lane = tid & 63, qd = lane >> 4, l15 = lane & 15;
  f32x4 acc[4] = {};
  for (int ks = 0; ks < 2; ++ks) {
    bf16x8 a = *(const bf16x8*)&As[w * 16 + l15][ks * 32 + qd * 8];
    for (int t = 0; t < 4; ++t) {
      bf16x8 b = *(const bf16x8*)&Bs[t * 16 + l15][ks * 32 + qd * 8];
      acc[t] = __builtin_amdgcn_mfma_f32_16x16x32_bf16(a, b, acc[t], 0, 0, 0);
    }
  }
  int n = m0 >> 10, s0 = m0 & 1023;
  if (mat == 2) {
    // transpose in LDS: As[d][s_local] then coalesced store to vtb[nh][d][s].
    __syncthreads();
    for (int t = 0; t < 4; ++t)
      for (int r = 0; r < 4; ++r)
        As[t * 16 + l15][w * 16 + qd * 4 + r] = f2bf(acc[t][r]);
    __syncthreads();
    int nh = n * H_ + h;
    for (int u = tid; u < 512; u += 256) {
      int d = u >> 3, seg = u & 7;
      *(int4*)&vtb[((size_t)nh * D_ + d) * SPAD_ + s0 + seg * 8] =
          *(const int4*)&As[d][seg * 8];
    }
    return;
  }
  for (int t = 0; t < 4; ++t)
    for (int r = 0; r < 4; ++r) {
      int s = s0 + w * 16 + qd * 4 + r;
      int d = t * 16 + l15;
      u16 val = f2bf(acc[t][r]);
      if (mat == 0)
        qb[((size_t)(n * H_ + h) * S_ + s) * D_ + d] = val;
      else
        kb[((size_t)(n * H_ + h) * SPAD_ + s) * D_ + d] = val;
    }
}

// Energy: Sb[nh][q][l] = q.k via MFMA.
// R8: global_load_lds(16B) staging into linear [64][64] LDS with XOR-granule
// swizzle (inverse-swz global source + swz fragment read; rule #21).
__global__ __launch_bounds__(256) void k_energy(const u16* qb, const u16* kb,
                                                u16* Sb) {
  __shared__ u16 As[64 * 64];
  __shared__ u16 Bs[64 * 64];
  int tid = threadIdx.x;
  int lin = blockIdx.x + 17 * (blockIdx.y + 16 * blockIdx.z);  // 17408
  lin = (lin & 7) * (17408 >> 3) + (lin >> 3);
  int l0 = (lin % 17) * 64;
  int t0 = lin / 17;
  int q0 = (t0 & 15) * 64;
  int nh = t0 >> 4;  // n*H + h
  const u16* qsrc = qb + ((size_t)nh * S_ + q0) * D_;
  const u16* ksrc = kb + ((size_t)nh * SPAD_ + l0) * D_;
  int w = tid >> 6, lane = tid & 63;
#pragma unroll
  for (int v = 0; v < 2; ++v) {
    int gi = (v * 4 + w) * 64 + lane;  // granule id 0..511
    int row = gi >> 3, g = gi & 7;
    int gsw = g ^ (row & 7);  // inverse-swizzled source granule
    glds16(&qsrc[row * D_ + gsw * 8], &As[(v * 4 + w) * 512]);
    glds16(&ksrc[row * D_ + gsw * 8], &Bs[(v * 4 + w) * 512]);
  }
  __syncthreads();
  int qd = lane >> 4, l15 = lane & 15;
  f32x4 acc[4] = {};
#pragma unroll
  for (int ks = 0; ks < 2; ++ks) {
    int ar = w * 16 + l15;
    bf16x8 a = *(const bf16x8*)&As[ar * 64 + ((ks * 4 + qd) ^ (ar & 7)) * 8];
#pragma unroll
    for (int t = 0; t < 4; ++t) {
      int br = t * 16 + l15;
      bf16x8 b = *(const bf16x8*)&Bs[br * 64 + ((ks * 4 + qd) ^ (br & 7)) * 8];
      acc[t] = __builtin_amdgcn_mfma_f32_16x16x32_bf16(a, b, acc[t], 0, 0, 0);
    }
  }
  for (int t = 0; t < 4; ++t)
    for (int r = 0; r < 4; ++r) {
      int q = q0 + w * 16 + qd * 4 + r;
      int l = l0 + t * 16 + l15;
      Sb[((size_t)nh * S_ + q) * SPAD_ + l] = f2bf(acc[t][r]);
    }
}

// Per (n,q): premix (W_pre + folded ALiBi), softmax over l<SP, postmix.
// No max pass (shift-invariance; bounded range). Weights via s_load.
__global__ __launch_bounds__(256) void k_smx(u16* __restrict__ Sb,
                                             const float* __restrict__ Wpre,
                                             const float* __restrict__ Wpost) {
  __shared__ __align__(16) float red[8][36];  // [head][group], 32 groups
  __shared__ __align__(16) float izf[8];      // 1/sum per head
  int tid = threadIdx.x;
  int n = blockIdx.x >> 10, q = blockIdx.x & 1023;
  const size_t hs = (size_t)S_ * SPAD_;
  u16* __restrict__ base = Sb + ((size_t)n * H_ * S_ + q) * SPAD_;
  // 1/sqrt(512) * log2(e): softmax in exp2 domain (exact same math).
  const float isc2 = 0.04419417382415922f * 1.4426950408889634f;

  int la = 4 * tid;
  bool hasB = (tid < 16);
  int lb = 1024 + tid;  // 16 valid prefix keys

  // Issue all global loads up front (MLP).
  uint2 ldA[8];
#pragma unroll
  for (int i = 0; i < 8; ++i) ldA[i] = *(const uint2*)(base + i * hs + la);
  u16 ldB[8];
  if (hasB) {
#pragma unroll
    for (int i = 0; i < 8; ++i) ldB[i] = base[i * hs + lb];
  }

  float bt[4];
#pragma unroll
  for (int j = 0; j < 4; ++j) bt[j] = -fabsf((float)(q - (la + j)));

  // ---------- premix chunk A (bias folded into inputs) ----------
  float eA[32];  // [o][4]
#pragma unroll
  for (int j = 0; j < 32; ++j) eA[j] = 0.f;
#pragma unroll
  for (int i = 0; i < 8; ++i) {
    const float ci = 1.0f / (float)(2 << i);  // 2^-(i+1), compile-time
    float x0 = bf2f((u16)(ldA[i].x & 0xffffu)) + bt[0] * ci;
    float x1 = bf2f((u16)(ldA[i].x >> 16)) + bt[1] * ci;
    float x2 = bf2f((u16)(ldA[i].y & 0xffffu)) + bt[2] * ci;
    float x3 = bf2f((u16)(ldA[i].y >> 16)) + bt[3] * ci;
#pragma unroll
    for (int o = 0; o < 8; ++o) {
      float wv = Wpre[o * 8 + i];  // uniform -> s_load, SGPR operand
      eA[4 * o + 0] += wv * x0;
      eA[4 * o + 1] += wv * x1;
      eA[4 * o + 2] += wv * x2;
      eA[4 * o + 3] += wv * x3;
    }
  }

  // ---------- premix tail: 16 prefix keys, 1 per thread, no bias ----------
  float eB[8];
  if (hasB) {
#pragma unroll
    for (int o = 0; o < 8; ++o) eB[o] = 0.f;
#pragma unroll
    for (int i = 0; i < 8; ++i) {
      float xi = bf2f(ldB[i]);
#pragma unroll
      for (int o = 0; o < 8; ++o) eB[o] += Wpre[o * 8 + i] * xi;
    }
  }

  // ---------- exp2 (no shift) + block-wide sum ----------
  float zl[8];
#pragma unroll
  for (int o = 0; o < 8; ++o) {
    float s = 0.f;
#pragma unroll
    for (int j = 0; j < 4; ++j) {
      eA[4 * o + j] = exp2v(eA[4 * o + j] * isc2);
      s += eA[4 * o + j];
    }
    zl[o] = s;
  }
  if (hasB) {
#pragma unroll
    for (int o = 0; o < 8; ++o) {
      eB[o] = exp2v(eB[o] * isc2);
      zl[o] += eB[o];
    }
  }
#pragma unroll
  for (int o = 0; o < 8; ++o)
    for (int mm = 1; mm < 8; mm <<= 1) zl[o] += __shfl_xor(zl[o], mm, 64);
  {
    int g = tid >> 3;
    if ((tid & 7) == 0) {
#pragma unroll
      for (int o = 0; o < 8; ++o) red[o][g] = zl[o];
    }
  }
  __syncthreads();
  if (tid < 64) {
    int o = tid >> 3, part = tid & 7;
    f32x4 pv = *(const f32x4*)&red[o][part * 4];
    float ps = (pv[0] + pv[1]) + (pv[2] + pv[3]);
    for (int mm = 1; mm < 8; mm <<= 1) ps += __shfl_xor(ps, mm, 64);
    if (part == 0) izf[o] = 1.0f / ps;
  }
  __syncthreads();

  f32x4 zlo = *(const f32x4*)&izf[0];
  f32x4 zhi = *(const f32x4*)&izf[4];

  // ---------- normalize + postmix + store, chunk A ----------
  {
#pragma unroll
    for (int o = 0; o < 8; ++o) {
      float iz = (o < 4) ? zlo[o & 3] : zhi[o & 3];
#pragma unroll
      for (int j = 0; j < 4; ++j) eA[4 * o + j] *= iz;
    }
#pragma unroll
    for (int o = 0; o < 8; ++o) {
      float p0 = 0.f, p1 = 0.f, p2 = 0.f, p3 = 0.f;
#pragma unroll
      for (int i = 0; i < 8; ++i) {
        float wv = Wpost[o * 8 + i];  // uniform -> s_load
        p0 += wv * eA[4 * i + 0];
        p1 += wv * eA[4 * i + 1];
        p2 += wv * eA[4 * i + 2];
        p3 += wv * eA[4 * i + 3];
      }
      uint2 u;
      u.x = cvtpk(p0, p1);
      u.y = cvtpk(p2, p3);
      *(uint2*)(base + o * hs + la) = u;
    }
  }
  // ---------- normalize + postmix + store, tail ----------
  if (hasB) {
#pragma unroll
    for (int o = 0; o < 8; ++o) {
      float iz = (o < 4) ? zlo[o & 3] : zhi[o & 3];
      eB[o] *= iz;
    }
#pragma unroll
    for (int o = 0; o < 8; ++o) {
      float p0 = 0.f;
#pragma unroll
      for (int i = 0; i < 8; ++i) p0 += Wpost[o * 8 + i] * eB[i];
      base[o * hs + lb] = f2bf(p0);
    }
  }
}

// AV: attb = attn @ vT. R8: glds16 staging + XOR-granule swizzle.
__global__ __launch_bounds__(256) void k_av(const u16* Sb, const u16* vtb,
                                            u16* attb) {
  __shared__ u16 As[64 * 64];
  __shared__ u16 Bs[64 * 64];
  int tid = threadIdx.x;
  int lin = blockIdx.x + 16 * blockIdx.y;  // 1024 blocks
  lin = (lin & 7) * (1024 >> 3) + (lin >> 3);
  int q0 = (lin & 15) * 64;
  int nh = lin >> 4;
  int n = nh >> 3, h = nh & 7;
  const u16* Ab = Sb + ((size_t)nh * S_ + q0) * SPAD_;
  const u16* Bb = vtb + (size_t)nh * D_ * SPAD_;
  int w = tid >> 6, lane = tid & 63, qd = lane >> 4, l15 = lane & 15;
  f32x4 acc[4] = {};
  for (int ks = 0; ks < 17; ++ks) {
    int k0 = ks * 64;
    __syncthreads();
#pragma unroll
    for (int v = 0; v < 2; ++v) {
      int gi = (v * 4 + w) * 64 + lane;
      int row = gi >> 3, g = gi & 7;
      int gsw = g ^ (row & 7);
      glds16(&Ab[(size_t)row * SPAD_ + k0 + gsw * 8], &As[(v * 4 + w) * 512]);
      glds16(&Bb[(size_t)row * SPAD_ + k0 + gsw * 8], &Bs[(v * 4 + w) * 512]);
    }
    __syncthreads();
#pragma unroll
    for (int k2 = 0; k2 < 2; ++k2) {
      int ar = w * 16 + l15;
      bf16x8 a = *(const bf16x8*)&As[ar * 64 + ((k2 * 4 + qd) ^ (ar & 7)) * 8];
#pragma unroll
      for (int t = 0; t < 4; ++t) {
        int br = t * 16 + l15;
        bf16x8 b =
            *(const bf16x8*)&Bs[br * 64 + ((k2 * 4 + qd) ^ (br & 7)) * 8];
        acc[t] = __builtin_amdgcn_mfma_f32_16x16x32_bf16(a, b, acc[t], 0, 0, 0);
      }
    }
  }
  for (int t = 0; t < 4; ++t)
    for (int r = 0; r < 4; ++r) {
      int q = q0 + w * 16 + qd * 4 + r;
      int c = h * 64 + t * 16 + l15;
      attb[((size_t)(n * S_ + q)) * C_ + c] = f2bf(acc[t][r]);
    }
}

// FC + residual: hp = x + att @ Wfc^T + bfc (fp32 out).
// R8: glds16 staging + XOR-granule swizzle.
__global__ __launch_bounds__(256) void k_fc(const u16* attb, const u16* Wfcb,
                                            const float* bfc, const float* x,
                                            float* hp) {
  __shared__ u16 As[64 * 64];
  __shared__ u16 Bs[64 * 64];
  int tid = threadIdx.x;
  int lin = blockIdx.x + 128 * blockIdx.y;  // 1024 blocks
  lin = (lin & 7) * (1024 >> 3) + (lin >> 3);
  int m0 = (lin & 127) * 64, n0 = (lin >> 7) * 64;
  int w = tid >> 6, lane = tid & 63, qd = lane >> 4, l15 = lane & 15;
  f32x4 acc[4] = {};
  for (int ks = 0; ks < 8; ++ks) {
    int k0 = ks * 64;
    __syncthreads();
#pragma unroll
    for (int v = 0; v < 2; ++v) {
      int gi = (v * 4 + w) * 64 + lane;
      int row = gi >> 3, g = gi & 7;
      int gsw = g ^ (row & 7);
      glds16(&attb[(size_t)(m0 + row) * C_ + k0 + gsw * 8],
             &As[(v * 4 + w) * 512]);
      glds16(&Wfcb[(size_t)(n0 + row) * C_ + k0 + gsw * 8],
             &Bs[(v * 4 + w) * 512]);
    }
    __syncthreads();
#pragma unroll
    for (int k2 = 0; k2 < 2; ++k2) {
      int ar = w * 16 + l15;
      bf16x8 a = *(const bf16x8*)&As[ar * 64 + ((k2 * 4 + qd) ^ (ar & 7)) * 8];
#pragma unroll
      for (int t = 0; t < 4; ++t) {
        int br = t * 16 + l15;
        bf16x8 b =
            *(const bf16x8*)&Bs[br * 64 + ((k2 * 4 + qd) ^ (br & 7)) * 8];
        acc[t] = __builtin_amdgcn_mfma_f32_16x16x32_bf16(a, b, acc[t], 0, 0, 0);
      }
    }
  }
  for (int t = 0; t < 4; ++t)
    for (int r = 0; r < 4; ++r) {
      int m = m0 + w * 16 + qd * 4 + r;
      int c = n0 + t * 16 + l15;
      hp[(size_t)m * C_ + c] = acc[t][r] + bfc[c] + x[(size_t)m * C_ + c];
    }
}

// LayerNorm over C per row; fp32 in, bf16 out.
__global__ __launch_bounds__(512) void k_ln(const float* hp, const float* g,
                                            const float* b, u16* hb) {
  __shared__ float r1[8], r2[8];
  int row = blockIdx.x, tid = threadIdx.x;
  int w = tid >> 6, lane = tid & 63;
  float v = hp[(size_t)row * C_ + tid];
  float s1 = v, s2 = v * v;
  for (int m = 1; m < 64; m <<= 1) {
    s1 += __shfl_xor(s1, m, 64);
    s2 += __shfl_xor(s2, m, 64);
  }
  if (lane == 0) {
    r1[w] = s1;
    r2[w] = s2;
  }
  __syncthreads();
  float t1 = 0.f, t2 = 0.f;
  for (int i = 0; i < 8; ++i) {
    t1 += r1[i];
    t2 += r2[i];
  }
  float mu = t1 * (1.0f / C_);
  float var = t2 * (1.0f / C_) - mu * mu;
  float o = (v - mu) * rsqrtf(var + 1e-5f) * g[tid] + b[tid];
  hb[(size_t)row * C_ + tid] = f2bf(o);
}

// Causal conv (K=3, left pad 2) as 3 accumulated MFMA NT-GEMMs.
// LDS-staged (halo zero-fill incompatible with glds), R6 form.
// mode 0: out = relu(acc+bias) -> outb bf16
// mode 1: out = relu(relu(acc+bias)+res) -> outf fp32
__global__ __launch_bounds__(256) void k_conv(const u16* in, const u16* wt,
                                              const float* bias,
                                              const u16* res, u16* outb,
                                              float* outf, int mode) {
  __shared__ u16 As[66][72];
  __shared__ u16 Bs[3][64][72];
  int tid = threadIdx.x;
  int lin = blockIdx.x + 128 * blockIdx.y;  // 1024 blocks
  lin = (lin & 7) * (1024 >> 3) + (lin >> 3);
  int m0 = (lin & 127) * 64, n0 = (lin >> 7) * 64;
  int n = m0 >> 10, s0 = m0 & 1023;
  int w = tid >> 6, lane = tid & 63, qd = lane >> 4, l15 = lane & 15;
  f32x4 acc[4] = {};
  for (int ks = 0; ks < 8; ++ks) {
    int k0 = ks * 64;
    __syncthreads();
    for (int u = tid; u < 528; u += 256) {
      int row = u >> 3, seg = u & 7;
      int s = s0 + row - 2;
      int4 pa;
      pa.x = pa.y = pa.z = pa.w = 0;
      if (s >= 0)
        pa = *(const int4*)&in[((size_t)(n * S_ + s)) * C_ + k0 + seg * 8];
      *(int4*)&As[row][seg * 8] = pa;
    }
    for (int u = tid; u < 1536; u += 256) {
      int tap = u >> 9, rr = (u >> 3) & 63, seg = u & 7;
      *(int4*)&Bs[tap][rr][seg * 8] = *(const int4*)&wt[
          (size_t)tap * C_ * C_ + (size_t)(n0 + rr) * C_ + k0 + seg * 8];
    }
    __syncthreads();
    for (int k2 = 0; k2 < 2; ++k2) {
      for (int tap = 0; tap < 3; ++tap) {
        bf16x8 a = *(const bf16x8*)&As[w * 16 + l15 + tap][k2 * 32 + qd * 8];
        for (int t = 0; t < 4; ++t) {
          bf16x8 b = *(const bf16x8*)&Bs[tap][t * 16 + l15][k2 * 32 + qd * 8];
          acc[t] =
              __builtin_amdgcn_mfma_f32_16x16x32_bf16(a, b, acc[t], 0, 0, 0);
        }
      }
    }
  }
  for (int t = 0; t < 4; ++t)
    for (int r = 0; r < 4; ++r) {
      int s = s0 + w * 16 + qd * 4 + r;
      int c = n0 + t * 16 + l15;
      float val = fmaxf(acc[t][r] + bias[c], 0.0f);
      size_t idx = ((size_t)(n * S_ + s)) * C_ + c;
      if (mode) {
        val = fmaxf(val + bf2f(res[idx]), 0.0f);
        outf[idx] = val;
      } else {
        outb[idx] = f2bf(val);
      }
    }
}

extern "C" void kernel_launch(void* const* d_in, const int* in_sizes, int n_in,
                              void* d_out, int out_size, void* d_ws,
                              size_t ws_size, hipStream_t stream) {
  int o = (in_sizes[1] == D_ * D_) ? 1 : 2;  // dict vs signature order
  const float* x = (const float*)d_in[0];
  const float* Wq = (const float*)d_in[o + 0];
  const float* Wk = (const float*)d_in[o + 1];
  const float* Wv = (const float*)d_in[o + 2];
  const float* Wfc = (const float*)d_in[o + 3];
  const float* bfc = (const float*)d_in[o + 4];
  const float* Wpre = (const float*)d_in[o + 5];
  const float* Wpost = (const float*)d_in[o + 6];
  const float* pk = (const float*)d_in[o + 7];
  const float* pv = (const float*)d_in[o + 8];
  const float* lng = (const float*)d_in[o + 9];
  const float* lnb = (const float*)d_in[o + 10];
  const float* c1w = (const float*)d_in[o + 11];
  const float* c1b = (const float*)d_in[o + 12];
  const float* c2w = (const float*)d_in[o + 13];
  const float* c2b = (const float*)d_in[o + 14];
  float* out = (float*)d_out;

  // Workspace ~215 MB (ws_size = 256 MiB per the harness poison fill).
  char* ws = (char*)d_ws;
  size_t off = 0;
  u16* qb = (u16*)(ws + off);   off += (size_t)B_ * H_ * S_ * D_ * 2;
  u16* kb = (u16*)(ws + off);   off += (size_t)B_ * H_ * SPAD_ * D_ * 2;
  u16* vtb = (u16*)(ws + off);  off += (size_t)B_ * H_ * D_ * SPAD_ * 2;
  u16* Sb = (u16*)(ws + off);   off += (size_t)B_ * H_ * S_ * SPAD_ * 2;  // 142.6MB
  u16* attb = (u16*)(ws + off); off += (size_t)B_ * S_ * C_ * 2;
  float* hp = (float*)(ws + off); off += (size_t)B_ * S_ * C_ * 4;
  u16* hb = (u16*)(ws + off);   off += (size_t)B_ * S_ * C_ * 2;
  u16* o1b = (u16*)(ws + off);  off += (size_t)B_ * S_ * C_ * 2;
  u16* wfcb = (u16*)(ws + off); off += (size_t)C_ * C_ * 2;
  u16* w1t = (u16*)(ws + off);  off += (size_t)KSZ * C_ * C_ * 2;
  u16* w2t = (u16*)(ws + off);  off += (size_t)KSZ * C_ * C_ * 2;
  u16* xb = (u16*)(ws + off);   off += (size_t)B_ * S_ * C_ * 2;
  u16* wb3 = (u16*)(ws + off);  off += (size_t)3 * D_ * D_ * 2;

  k_prep<<<10288, 256, 0, stream>>>(x, xb, Wfc, wfcb, c1w, w1t, c2w, w2t,
                                    Wq, Wk, Wv, wb3, pk, pv, kb, vtb);
  k_qkv<<<dim3(128, 24), 256, 0, stream>>>(xb, wb3, qb, kb, vtb);
  k_energy<<<dim3(17, 16, 64), 256, 0, stream>>>(qb, kb, Sb);
  k_smx<<<8192, 256, 0, stream>>>(Sb, Wpre, Wpost);
  k_av<<<dim3(16, 64), 256, 0, stream>>>(Sb, vtb, attb);
  k_fc<<<dim3(128, 8), 256, 0, stream>>>(attb, wfcb, bfc, x, hp);
  k_ln<<<8192, 512, 0, stream>>>(hp, lng, lnb, hb);
  k_conv<<<dim3(128, 8), 256, 0, stream>>>(hb, w1t, c1b, (const u16*)0, o1b,
                                           (float*)0, 0);
  k_conv<<<dim3(128, 8), 256, 0, stream>>>(o1b, w2t, c2b, hb, (u16*)0, out, 1);
}

// Round 9
// 288.322 us; speedup vs baseline: 1.5856x; 1.1290x over previous
//
#include <hip/hip_runtime.h>

#define B_ 8
#define S_ 1024
#define C_ 512
#define H_ 8
#define D_ 64
#define P_ 16
#define SP_ 1040    // valid keys: S + P
#define SPAD_ 1088  // score-matrix row stride: 17*64
#define KSZ 3

typedef unsigned short u16;
typedef unsigned int u32;
typedef short bf16x8 __attribute__((ext_vector_type(8)));
typedef float f32x4 __attribute__((ext_vector_type(4)));

__device__ __forceinline__ float bf2f(u16 u) {
  return __uint_as_float(((unsigned int)u) << 16);
}
__device__ __forceinline__ u16 f2bf(float f) {
  unsigned int u = __float_as_uint(f);
  return (u16)((u + 0x7fffu + ((u >> 16) & 1u)) >> 16);
}
// Packed fp32->bf16 RNE convert: 1 instr for 2 values (same rounding as f2bf).
__device__ __forceinline__ unsigned int cvtpk(float lo, float hi) {
  unsigned int r;
  asm("v_cvt_pk_bf16_f32 %0, %1, %2" : "=v"(r) : "v"(lo), "v"(hi));
  return r;
}
// Raw v_exp_f32: computes 2^x in one instruction.
__device__ __forceinline__ float exp2v(float x) {
  float r;
  asm("v_exp_f32 %0, %1" : "=v"(r) : "v"(x));
  return r;
}
// Async global->LDS, 16B per lane. LDS dest is wave-uniform base + lane*16.
__device__ __forceinline__ void glds16(const u16* g, u16* l) {
  __builtin_amdgcn_global_load_lds(
      (const __attribute__((address_space(1))) u32*)g,
      (__attribute__((address_space(3))) u32*)l, 16, 0, 0);
}
// Round 8 consecutive fp32 to bf16, packed as int4 (8 x u16).
__device__ __forceinline__ int4 pack8(const float* p) {
  int4 r;
  r.x = (int)cvtpk(p[0], p[1]);
  r.y = (int)cvtpk(p[2], p[3]);
  r.z = (int)cvtpk(p[4], p[5]);
  r.w = (int)cvtpk(p[6], p[7]);
  return r;
}

// Merged prep: x cvt | Wfc cvt + conv repacks | k/v prefix | Wq/Wk/Wv cvt.
__global__ void k_prep(const float* x, u16* xb, const float* Wfc, u16* wfcb,
                       const float* c1w, u16* w1t, const float* c2w, u16* w2t,
                       const float* Wq, const float* Wk, const float* Wv,
                       u16* wb3, const float* pk, const float* pv, u16* kb,
                       u16* vtb) {
  int b = blockIdx.x, tid = threadIdx.x;
  if (b < 2048) {  // x fp32 -> bf16, 8 elems/thread
    int gid = b * 256 + tid;
    *(int4*)&xb[(size_t)gid * 8] = pack8(&x[(size_t)gid * 8]);
    return;
  }
  if (b < 9216) {  // Wfc cvt + conv1/conv2 repack
    int gid = (b - 2048) * 256 + tid;
    if (gid < C_ * C_) {
      wfcb[gid] = f2bf(Wfc[gid]);
      return;
    }
    int r = gid - C_ * C_;
    const float* src = c1w;
    u16* dst = w1t;
    if (r >= C_ * C_ * KSZ) {
      r -= C_ * C_ * KSZ;
      src = c2w;
      dst = w2t;
    }
    int co = r / (C_ * KSZ);
    int rem = r - co * (C_ * KSZ);
    int ci = rem / KSZ;
    int tap = rem - ci * KSZ;
    dst[(size_t)tap * C_ * C_ + co * C_ + ci] = f2bf(src[r]);
    return;
  }
  if (b < 10240) {  // prefix rows: kb[S..SPAD) + vtb[.., 1024..1088)
    int g = (b - 9216) * 256 + tid;  // 262144
    {
      int d = g & 63, t = g >> 6, p = t & 63, nh = t >> 6;
      kb[((size_t)nh * SPAD_ + S_ + p) * D_ + d] =
          (p < P_) ? f2bf(pk[p * 64 + d]) : 0;
    }
    {
      int p = g & 63, d = (g >> 6) & 63, nh = g >> 12;
      vtb[((size_t)nh * D_ + d) * SPAD_ + S_ + p] =
          (p < P_) ? f2bf(pv[p * 64 + d]) : 0;
    }
    return;
  }
  {  // Wq/Wk/Wv -> bf16 wb3[mat][64][64]
    int e = (b - 10240) * 256 + tid;  // 12288
    int mat = e >> 12, idx = e & 4095;
    const float* W = (mat == 0) ? Wq : ((mat == 1) ? Wk : Wv);
    wb3[e] = f2bf(W[idx]);
  }
}

// QKV: R9 fused -- one block computes Q, K, V for an (m-tile, head).
// x-tile staged ONCE via glds16 (was read 3x); 24 MFMA/wave; V written
// transposed to vtb via padded-LDS bounce (scratch in Bs).
__global__ __launch_bounds__(256) void k_qkv(
    const u16* xb, const u16* wb3, u16* qb, u16* kb, u16* vtb) {
  __shared__ u16 As[64 * 64];
  __shared__ u16 Bs[3][64 * 64];
  int tid = threadIdx.x;
  int m0 = blockIdx.x * 64;  // 128 m-tiles
  int h = blockIdx.y;
  const u16* xsrc = xb + (size_t)m0 * C_ + h * 64;
  int w = tid >> 6, lane = tid & 63;
#pragma unroll
  for (int v = 0; v < 2; ++v) {
    int gi = (v * 4 + w) * 64 + lane;
    int row = gi >> 3, g = gi & 7;
    int gsw = g ^ (row & 7);
    glds16(&xsrc[(size_t)row * C_ + gsw * 8], &As[(v * 4 + w) * 512]);
  }
#pragma unroll
  for (int v = 0; v < 6; ++v) {
    int ci = v * 4 + w;  // 0..23
    int mat = ci >> 3, c8 = ci & 7;
    int gi = c8 * 64 + lane;
    int row = gi >> 3, g = gi & 7;
    int gsw = g ^ (row & 7);
    glds16(&wb3[(mat << 12) + row * 64 + gsw * 8], &Bs[mat][c8 * 512]);
  }
  __syncthreads();
  int qd = lane >> 4, l15 = lane & 15;
  f32x4 acc[3][4] = {};
#pragma unroll
  for (int ks = 0; ks < 2; ++ks) {
    int ar = w * 16 + l15;
    bf16x8 a = *(const bf16x8*)&As[ar * 64 + ((ks * 4 + qd) ^ (ar & 7)) * 8];
#pragma unroll
    for (int mat = 0; mat < 3; ++mat)
#pragma unroll
      for (int t = 0; t < 4; ++t) {
        int br = t * 16 + l15;
        bf16x8 b =
            *(const bf16x8*)&Bs[mat][br * 64 + ((ks * 4 + qd) ^ (br & 7)) * 8];
        acc[mat][t] =
            __builtin_amdgcn_mfma_f32_16x16x32_bf16(a, b, acc[mat][t], 0, 0, 0);
      }
  }
  int n = m0 >> 10, s0 = m0 & 1023;
  int nh = n * H_ + h;
  for (int t = 0; t < 4; ++t)
    for (int r = 0; r < 4; ++r) {
      int s = s0 + w * 16 + qd * 4 + r;
      int d = t * 16 + l15;
      qb[((size_t)nh * S_ + s) * D_ + d] = f2bf(acc[0][t][r]);
      kb[((size_t)nh * SPAD_ + s) * D_ + d] = f2bf(acc[1][t][r]);
    }
  // V transpose bounce: padded [64][72] view over Bs scratch (conflict-free).
  u16(*tr)[72] = (u16(*)[72]) & Bs[0][0];  // 9216 B < 24 KB scratch
  __syncthreads();
  for (int t = 0; t < 4; ++t)
    for (int r = 0; r < 4; ++r)
      tr[t * 16 + l15][w * 16 + qd * 4 + r] = f2bf(acc[2][t][r]);
  __syncthreads();
  for (int u = tid; u < 512; u += 256) {
    int d = u >> 3, seg = u & 7;
    *(int4*)&vtb[((size_t)nh * D_ + d) * SPAD_ + s0 + seg * 8] =
        *(const int4*)&tr[d][seg * 8];
  }
}

// Energy: Sb[nh][q][l] = q.k via MFMA. glds16 + XOR-granule swizzle (R8).
__global__ __launch_bounds__(256) void k_energy(const u16* qb, const u16* kb,
                                                u16* Sb) {
  __shared__ u16 As[64 * 64];
  __shared__ u16 Bs[64 * 64];
  int tid = threadIdx.x;
  int lin = blockIdx.x + 17 * (blockIdx.y + 16 * blockIdx.z);  // 17408
  lin = (lin & 7) * (17408 >> 3) + (lin >> 3);
  int l0 = (lin % 17) * 64;
  int t0 = lin / 17;
  int q0 = (t0 & 15) * 64;
  int nh = t0 >> 4;  // n*H + h
  const u16* qsrc = qb + ((size_t)nh * S_ + q0) * D_;
  const u16* ksrc = kb + ((size_t)nh * SPAD_ + l0) * D_;
  int w = tid >> 6, lane = tid & 63;
#pragma unroll
  for (int v = 0; v < 2; ++v) {
    int gi = (v * 4 + w) * 64 + lane;  // granule id 0..511
    int row = gi >> 3, g = gi & 7;
    int gsw = g ^ (row & 7);  // inverse-swizzled source granule
    glds16(&qsrc[row * D_ + gsw * 8], &As[(v * 4 + w) * 512]);
    glds16(&ksrc[row * D_ + gsw * 8], &Bs[(v * 4 + w) * 512]);
  }
  __syncthreads();
  int qd = lane >> 4, l15 = lane & 15;
  f32x4 acc[4] = {};
#pragma unroll
  for (int ks = 0; ks < 2; ++ks) {
    int ar = w * 16 + l15;
    bf16x8 a = *(const bf16x8*)&As[ar * 64 + ((ks * 4 + qd) ^ (ar & 7)) * 8];
#pragma unroll
    for (int t = 0; t < 4; ++t) {
      int br = t * 16 + l15;
      bf16x8 b = *(const bf16x8*)&Bs[br * 64 + ((ks * 4 + qd) ^ (br & 7)) * 8];
      acc[t] = __builtin_amdgcn_mfma_f32_16x16x32_bf16(a, b, acc[t], 0, 0, 0);
    }
  }
  for (int t = 0; t < 4; ++t)
    for (int r = 0; r < 4; ++r) {
      int q = q0 + w * 16 + qd * 4 + r;
      int l = l0 + t * 16 + l15;
      Sb[((size_t)nh * S_ + q) * SPAD_ + l] = f2bf(acc[t][r]);
    }
}

// Per (n,q): premix (W_pre + folded ALiBi), softmax over l<SP, postmix.
// No max pass (shift-invariance; bounded range). Weights via s_load.
__global__ __launch_bounds__(256) void k_smx(u16* __restrict__ Sb,
                                             const float* __restrict__ Wpre,
                                             const float* __restrict__ Wpost) {
  __shared__ __align__(16) float red[8][36];  // [head][group], 32 groups
  __shared__ __align__(16) float izf[8];      // 1/sum per head
  int tid = threadIdx.x;
  int n = blockIdx.x >> 10, q = blockIdx.x & 1023;
  const size_t hs = (size_t)S_ * SPAD_;
  u16* __restrict__ base = Sb + ((size_t)n * H_ * S_ + q) * SPAD_;
  // 1/sqrt(512) * log2(e): softmax in exp2 domain (exact same math).
  const float isc2 = 0.04419417382415922f * 1.4426950408889634f;

  int la = 4 * tid;
  bool hasB = (tid < 16);
  int lb = 1024 + tid;  // 16 valid prefix keys

  // Issue all global loads up front (MLP).
  uint2 ldA[8];
#pragma unroll
  for (int i = 0; i < 8; ++i) ldA[i] = *(const uint2*)(base + i * hs + la);
  u16 ldB[8];
  if (hasB) {
#pragma unroll
    for (int i = 0; i < 8; ++i) ldB[i] = base[i * hs + lb];
  }

  float bt[4];
#pragma unroll
  for (int j = 0; j < 4; ++j) bt[j] = -fabsf((float)(q - (la + j)));

  // ---------- premix chunk A (bias folded into inputs) ----------
  float eA[32];  // [o][4]
#pragma unroll
  for (int j = 0; j < 32; ++j) eA[j] = 0.f;
#pragma unroll
  for (int i = 0; i < 8; ++i) {
    const float ci = 1.0f / (float)(2 << i);  // 2^-(i+1), compile-time
    float x0 = bf2f((u16)(ldA[i].x & 0xffffu)) + bt[0] * ci;
    float x1 = bf2f((u16)(ldA[i].x >> 16)) + bt[1] * ci;
    float x2 = bf2f((u16)(ldA[i].y & 0xffffu)) + bt[2] * ci;
    float x3 = bf2f((u16)(ldA[i].y >> 16)) + bt[3] * ci;
#pragma unroll
    for (int o = 0; o < 8; ++o) {
      float wv = Wpre[o * 8 + i];  // uniform -> s_load, SGPR operand
      eA[4 * o + 0] += wv * x0;
      eA[4 * o + 1] += wv * x1;
      eA[4 * o + 2] += wv * x2;
      eA[4 * o + 3] += wv * x3;
    }
  }

  // ---------- premix tail: 16 prefix keys, 1 per thread, no bias ----------
  float eB[8];
  if (hasB) {
#pragma unroll
    for (int o = 0; o < 8; ++o) eB[o] = 0.f;
#pragma unroll
    for (int i = 0; i < 8; ++i) {
      float xi = bf2f(ldB[i]);
#pragma unroll
      for (int o = 0; o < 8; ++o) eB[o] += Wpre[o * 8 + i] * xi;
    }
  }

  // ---------- exp2 (no shift) + block-wide sum ----------
  float zl[8];
#pragma unroll
  for (int o = 0; o < 8; ++o) {
    float s = 0.f;
#pragma unroll
    for (int j = 0; j < 4; ++j) {
      eA[4 * o + j] = exp2v(eA[4 * o + j] * isc2);
      s += eA[4 * o + j];
    }
    zl[o] = s;
  }
  if (hasB) {
#pragma unroll
    for (int o = 0; o < 8; ++o) {
      eB[o] = exp2v(eB[o] * isc2);
      zl[o] += eB[o];
    }
  }
#pragma unroll
  for (int o = 0; o < 8; ++o)
    for (int mm = 1; mm < 8; mm <<= 1) zl[o] += __shfl_xor(zl[o], mm, 64);
  {
    int g = tid >> 3;
    if ((tid & 7) == 0) {
#pragma unroll
      for (int o = 0; o < 8; ++o) red[o][g] = zl[o];
    }
  }
  __syncthreads();
  if (tid < 64) {
    int o = tid >> 3, part = tid & 7;
    f32x4 pv = *(const f32x4*)&red[o][part * 4];
    float ps = (pv[0] + pv[1]) + (pv[2] + pv[3]);
    for (int mm = 1; mm < 8; mm <<= 1) ps += __shfl_xor(ps, mm, 64);
    if (part == 0) izf[o] = 1.0f / ps;
  }
  __syncthreads();

  f32x4 zlo = *(const f32x4*)&izf[0];
  f32x4 zhi = *(const f32x4*)&izf[4];

  // ---------- normalize + postmix + store, chunk A ----------
  {
#pragma unroll
    for (int o = 0; o < 8; ++o) {
      float iz = (o < 4) ? zlo[o & 3] : zhi[o & 3];
#pragma unroll
      for (int j = 0; j < 4; ++j) eA[4 * o + j] *= iz;
    }
#pragma unroll
    for (int o = 0; o < 8; ++o) {
      float p0 = 0.f, p1 = 0.f, p2 = 0.f, p3 = 0.f;
#pragma unroll
      for (int i = 0; i < 8; ++i) {
        float wv = Wpost[o * 8 + i];  // uniform -> s_load
        p0 += wv * eA[4 * i + 0];
        p1 += wv * eA[4 * i + 1];
        p2 += wv * eA[4 * i + 2];
        p3 += wv * eA[4 * i + 3];
      }
      uint2 u;
      u.x = cvtpk(p0, p1);
      u.y = cvtpk(p2, p3);
      *(uint2*)(base + o * hs + la) = u;
    }
  }
  // ---------- normalize + postmix + store, tail ----------
  if (hasB) {
#pragma unroll
    for (int o = 0; o < 8; ++o) {
      float iz = (o < 4) ? zlo[o & 3] : zhi[o & 3];
      eB[o] *= iz;
    }
#pragma unroll
    for (int o = 0; o < 8; ++o) {
      float p0 = 0.f;
#pragma unroll
      for (int i = 0; i < 8; ++i) p0 += Wpost[o * 8 + i] * eB[i];
      base[o * hs + lb] = f2bf(p0);
    }
  }
}

// AV: attb = attn @ vT. glds16 + XOR-granule swizzle (R8).
__global__ __launch_bounds__(256) void k_av(const u16* Sb, const u16* vtb,
                                            u16* attb) {
  __shared__ u16 As[64 * 64];
  __shared__ u16 Bs[64 * 64];
  int tid = threadIdx.x;
  int lin = blockIdx.x + 16 * blockIdx.y;  // 1024 blocks
  lin = (lin & 7) * (1024 >> 3) + (lin >> 3);
  int q0 = (lin & 15) * 64;
  int nh = lin >> 4;
  int n = nh >> 3, h = nh & 7;
  const u16* Ab = Sb + ((size_t)nh * S_ + q0) * SPAD_;
  const u16* Bb = vtb + (size_t)nh * D_ * SPAD_;
  int w = tid >> 6, lane = tid & 63, qd = lane >> 4, l15 = lane & 15;
  f32x4 acc[4] = {};
  for (int ks = 0; ks < 17; ++ks) {
    int k0 = ks * 64;
    __syncthreads();
#pragma unroll
    for (int v = 0; v < 2; ++v) {
      int gi = (v * 4 + w) * 64 + lane;
      int row = gi >> 3, g = gi & 7;
      int gsw = g ^ (row & 7);
      glds16(&Ab[(size_t)row * SPAD_ + k0 + gsw * 8], &As[(v * 4 + w) * 512]);
      glds16(&Bb[(size_t)row * SPAD_ + k0 + gsw * 8], &Bs[(v * 4 + w) * 512]);
    }
    __syncthreads();
#pragma unroll
    for (int k2 = 0; k2 < 2; ++k2) {
      int ar = w * 16 + l15;
      bf16x8 a = *(const bf16x8*)&As[ar * 64 + ((k2 * 4 + qd) ^ (ar & 7)) * 8];
#pragma unroll
      for (int t = 0; t < 4; ++t) {
        int br = t * 16 + l15;
        bf16x8 b =
            *(const bf16x8*)&Bs[br * 64 + ((k2 * 4 + qd) ^ (br & 7)) * 8];
        acc[t] = __builtin_amdgcn_mfma_f32_16x16x32_bf16(a, b, acc[t], 0, 0, 0);
      }
    }
  }
  for (int t = 0; t < 4; ++t)
    for (int r = 0; r < 4; ++r) {
      int q = q0 + w * 16 + qd * 4 + r;
      int c = h * 64 + t * 16 + l15;
      attb[((size_t)(n * S_ + q)) * C_ + c] = f2bf(acc[t][r]);
    }
}

// FC + residual: hp = x + att @ Wfc^T + bfc (fp32 out). glds16 (R8).
__global__ __launch_bounds__(256) void k_fc(const u16* attb, const u16* Wfcb,
                                            const float* bfc, const float* x,
                                            float* hp) {
  __shared__ u16 As[64 * 64];
  __shared__ u16 Bs[64 * 64];
  int tid = threadIdx.x;
  int lin = blockIdx.x + 128 * blockIdx.y;  // 1024 blocks
  lin = (lin & 7) * (1024 >> 3) + (lin >> 3);
  int m0 = (lin & 127) * 64, n0 = (lin >> 7) * 64;
  int w = tid >> 6, lane = tid & 63, qd = lane >> 4, l15 = lane & 15;
  f32x4 acc[4] = {};
  for (int ks = 0; ks < 8; ++ks) {
    int k0 = ks * 64;
    __syncthreads();
#pragma unroll
    for (int v = 0; v < 2; ++v) {
      int gi = (v * 4 + w) * 64 + lane;
      int row = gi >> 3, g = gi & 7;
      int gsw = g ^ (row & 7);
      glds16(&attb[(size_t)(m0 + row) * C_ + k0 + gsw * 8],
             &As[(v * 4 + w) * 512]);
      glds16(&Wfcb[(size_t)(n0 + row) * C_ + k0 + gsw * 8],
             &Bs[(v * 4 + w) * 512]);
    }
    __syncthreads();
#pragma unroll
    for (int k2 = 0; k2 < 2; ++k2) {
      int ar = w * 16 + l15;
      bf16x8 a = *(const bf16x8*)&As[ar * 64 + ((k2 * 4 + qd) ^ (ar & 7)) * 8];
#pragma unroll
      for (int t = 0; t < 4; ++t) {
        int br = t * 16 + l15;
        bf16x8 b =
            *(const bf16x8*)&Bs[br * 64 + ((k2 * 4 + qd) ^ (br & 7)) * 8];
        acc[t] = __builtin_amdgcn_mfma_f32_16x16x32_bf16(a, b, acc[t], 0, 0, 0);
      }
    }
  }
  for (int t = 0; t < 4; ++t)
    for (int r = 0; r < 4; ++r) {
      int m = m0 + w * 16 + qd * 4 + r;
      int c = n0 + t * 16 + l15;
      hp[(size_t)m * C_ + c] = acc[t][r] + bfc[c] + x[(size_t)m * C_ + c];
    }
}

// LayerNorm over C per row; fp32 in, bf16 out.
__global__ __launch_bounds__(512) void k_ln(const float* hp, const float* g,
                                            const float* b, u16* hb) {
  __shared__ float r1[8], r2[8];
  int row = blockIdx.x, tid = threadIdx.x;
  int w = tid >> 6, lane = tid & 63;
  float v = hp[(size_t)row * C_ + tid];
  float s1 = v, s2 = v * v;
  for (int m = 1; m < 64; m <<= 1) {
    s1 += __shfl_xor(s1, m, 64);
    s2 += __shfl_xor(s2, m, 64);
  }
  if (lane == 0) {
    r1[w] = s1;
    r2[w] = s2;
  }
  __syncthreads();
  float t1 = 0.f, t2 = 0.f;
  for (int i = 0; i < 8; ++i) {
    t1 += r1[i];
    t2 += r2[i];
  }
  float mu = t1 * (1.0f / C_);
  float var = t2 * (1.0f / C_) - mu * mu;
  float o = (v - mu) * rsqrtf(var + 1e-5f) * g[tid] + b[tid];
  hb[(size_t)row * C_ + tid] = f2bf(o);
}

// Causal conv (K=3, left pad 2) as 3 accumulated MFMA NT-GEMMs.
// R9: glds16 staging for main A rows (2..65, always in-bounds) and all 3
// B tap-tiles; only the 2 halo rows (s<0 zero-fill) staged manually with
// the same granule XOR. Same swizzle involution as k_energy (R8-verified).
// mode 0: out = relu(acc+bias) -> outb bf16
// mode 1: out = relu(relu(acc+bias)+res) -> outf fp32
__global__ __launch_bounds__(256) void k_conv(const u16* in, const u16* wt,
                                              const float* bias,
                                              const u16* res, u16* outb,
                                              float* outf, int mode) {
  __shared__ u16 As[66 * 64];
  __shared__ u16 Bs[3][64 * 64];
  int tid = threadIdx.x;
  int lin = blockIdx.x + 128 * blockIdx.y;  // 1024 blocks
  lin = (lin & 7) * (1024 >> 3) + (lin >> 3);
  int m0 = (lin & 127) * 64, n0 = (lin >> 7) * 64;
  int n = m0 >> 10, s0 = m0 & 1023;
  int w = tid >> 6, lane = tid & 63, qd = lane >> 4, l15 = lane & 15;
  f32x4 acc[4] = {};
  for (int ks = 0; ks < 8; ++ks) {
    int k0 = ks * 64;
    __syncthreads();
    // main rows: LDS rows 2..65 = global s0..s0+63 (always valid)
#pragma unroll
    for (int v = 0; v < 2; ++v) {
      int gi = (v * 4 + w) * 64 + lane;
      int row = gi >> 3, g = gi & 7;       // row 0..63 -> LDS row row+2
      int gsw = g ^ ((row + 2) & 7);
      glds16(&in[((size_t)(n * S_ + s0 + row)) * C_ + k0 + gsw * 8],
             &As[128 + (v * 4 + w) * 512]);
    }
    // B: 3 taps x 8 chunks = 24 glds (6 per wave)
#pragma unroll
    for (int v = 0; v < 6; ++v) {
      int ci = v * 4 + w;
      int tap = ci >> 3, c8 = ci & 7;
      int gi = c8 * 64 + lane;
      int row = gi >> 3, g = gi & 7;
      int gsw = g ^ (row & 7);
      glds16(&wt[(size_t)tap * C_ * C_ + (size_t)(n0 + row) * C_ + k0 +
                 gsw * 8],
             &Bs[tap][c8 * 512]);
    }
    // halo rows 0..1 (global s0-2, s0-1), zero-filled when s<0
    if (tid < 16) {
      int row = tid >> 3, g = tid & 7;
      int s = s0 - 2 + row;
      int4 pa;
      pa.x = pa.y = pa.z = pa.w = 0;
      if (s >= 0)
        pa = *(const int4*)&in[((size_t)(n * S_ + s)) * C_ + k0 + g * 8];
      *(int4*)&As[row * 64 + (g ^ row) * 8] = pa;  // dest granule ^= row(&7)
    }
    __syncthreads();
#pragma unroll
    for (int k2 = 0; k2 < 2; ++k2) {
      for (int tap = 0; tap < 3; ++tap) {
        int ar = w * 16 + l15 + tap;  // LDS row; global s = s0 + ar - 2
        bf16x8 a =
            *(const bf16x8*)&As[ar * 64 + ((k2 * 4 + qd) ^ (ar & 7)) * 8];
        for (int t = 0; t < 4; ++t) {
          int br = t * 16 + l15;
          bf16x8 b = *(const bf16x8*)&Bs[tap][br * 64 +
                                             ((k2 * 4 + qd) ^ (br & 7)) * 8];
          acc[t] =
              __builtin_amdgcn_mfma_f32_16x16x32_bf16(a, b, acc[t], 0, 0, 0);
        }
      }
    }
  }
  for (int t = 0; t < 4; ++t)
    for (int r = 0; r < 4; ++r) {
      int s = s0 + w * 16 + qd * 4 + r;
      int c = n0 + t * 16 + l15;
      float val = fmaxf(acc[t][r] + bias[c], 0.0f);
      size_t idx = ((size_t)(n * S_ + s)) * C_ + c;
      if (mode) {
        val = fmaxf(val + bf2f(res[idx]), 0.0f);
        outf[idx] = val;
      } else {
        outb[idx] = f2bf(val);
      }
    }
}

extern "C" void kernel_launch(void* const* d_in, const int* in_sizes, int n_in,
                              void* d_out, int out_size, void* d_ws,
                              size_t ws_size, hipStream_t stream) {
  int o = (in_sizes[1] == D_ * D_) ? 1 : 2;  // dict vs signature order
  const float* x = (const float*)d_in[0];
  const float* Wq = (const float*)d_in[o + 0];
  const float* Wk = (const float*)d_in[o + 1];
  const float* Wv = (const float*)d_in[o + 2];
  const float* Wfc = (const float*)d_in[o + 3];
  const float* bfc = (const float*)d_in[o + 4];
  const float* Wpre = (const float*)d_in[o + 5];
  const float* Wpost = (const float*)d_in[o + 6];
  const float* pk = (const float*)d_in[o + 7];
  const float* pv = (const float*)d_in[o + 8];
  const float* lng = (const float*)d_in[o + 9];
  const float* lnb = (const float*)d_in[o + 10];
  const float* c1w = (const float*)d_in[o + 11];
  const float* c1b = (const float*)d_in[o + 12];
  const float* c2w = (const float*)d_in[o + 13];
  const float* c2b = (const float*)d_in[o + 14];
  float* out = (float*)d_out;

  // Workspace ~215 MB (ws_size = 256 MiB per the harness poison fill).
  char* ws = (char*)d_ws;
  size_t off = 0;
  u16* qb = (u16*)(ws + off);   off += (size_t)B_ * H_ * S_ * D_ * 2;
  u16* kb = (u16*)(ws + off);   off += (size_t)B_ * H_ * SPAD_ * D_ * 2;
  u16* vtb = (u16*)(ws + off);  off += (size_t)B_ * H_ * D_ * SPAD_ * 2;
  u16* Sb = (u16*)(ws + off);   off += (size_t)B_ * H_ * S_ * SPAD_ * 2;  // 142.6MB
  u16* attb = (u16*)(ws + off); off += (size_t)B_ * S_ * C_ * 2;
  float* hp = (float*)(ws + off); off += (size_t)B_ * S_ * C_ * 4;
  u16* hb = (u16*)(ws + off);   off += (size_t)B_ * S_ * C_ * 2;
  u16* o1b = (u16*)(ws + off);  off += (size_t)B_ * S_ * C_ * 2;
  u16* wfcb = (u16*)(ws + off); off += (size_t)C_ * C_ * 2;
  u16* w1t = (u16*)(ws + off);  off += (size_t)KSZ * C_ * C_ * 2;
  u16* w2t = (u16*)(ws + off);  off += (size_t)KSZ * C_ * C_ * 2;
  u16* xb = (u16*)(ws + off);   off += (size_t)B_ * S_ * C_ * 2;
  u16* wb3 = (u16*)(ws + off);  off += (size_t)3 * D_ * D_ * 2;

  k_prep<<<10288, 256, 0, stream>>>(x, xb, Wfc, wfcb, c1w, w1t, c2w, w2t,
                                    Wq, Wk, Wv, wb3, pk, pv, kb, vtb);
  k_qkv<<<dim3(128, 8), 256, 0, stream>>>(xb, wb3, qb, kb, vtb);
  k_energy<<<dim3(17, 16, 64), 256, 0, stream>>>(qb, kb, Sb);
  k_smx<<<8192, 256, 0, stream>>>(Sb, Wpre, Wpost);
  k_av<<<dim3(16, 64), 256, 0, stream>>>(Sb, vtb, attb);
  k_fc<<<dim3(128, 8), 256, 0, stream>>>(attb, wfcb, bfc, x, hp);
  k_ln<<<8192, 512, 0, stream>>>(hp, lng, lnb, hb);
  k_conv<<<dim3(128, 8), 256, 0, stream>>>(hb, w1t, c1b, (const u16*)0, o1b,
                                           (float*)0, 0);
  k_conv<<<dim3(128, 8), 256, 0, stream>>>(o1b, w2t, c2b, hb, (u16*)0, out, 1);
}